// Round 1
// baseline (9421.095 us; speedup 1.0000x reference)
//
#include <hip/hip_runtime.h>
#include <hip/hip_bf16.h>
#include <math.h>

#define B_    2048
#define ZD_   256
#define H_    1024
#define E_    96
#define V_    512
#define BEATS_ 4
#define TICKS_ 6
#define H3_   3072
#define W0_   25165824UL   // B*24*V, start of samples section in d_out

__device__ __forceinline__ float sigmoidf_(float x){ return 1.f/(1.f+expf(-x)); }
__device__ __forceinline__ float seluf_(float x){
    const float a = 1.6732632423543772f, s = 1.0507009873554805f;
    return x > 0.f ? s*x : s*a*expm1f(x);
}

// ---------------------------------------------------------------------------
// Tiled fp32 GEMM:  C[M,N] = act( A[M,K] * B + bias + pre )
//  BT=0: B is K x N row-major (ldb)          (NN)
//  BT=1: B is N x K row-major (ldb, +boff)   (NT: C[m][n] = sum_k A[m][k]*B[n][boff+k])
//  EPI: 0 none, 1 selu, 2 relu.  BIAS: add bias[n].  PRE: add pre[m][n] (ldp).
// Requires: M%BM==0, N%BN==0, K%BK==0, lda/ldb/ldc/ldp %4==0, boff%4==0.
// ---------------------------------------------------------------------------
template<int BM,int BN,int BK,int TM,int TN,int BT,int EPI,int BIAS,int PRE>
__global__ __launch_bounds__((BM/TM)*(BN/TN))
void gemm_k(const float* __restrict__ A, int lda,
            const float* __restrict__ Bp, int ldb, int boff,
            const float* __restrict__ bias,
            const float* __restrict__ pre, int ldp,
            float* __restrict__ C, int ldc,
            int M, int N, int K)
{
    constexpr int NTH = (BM/TM)*(BN/TN);
    constexpr int LAS = BM + 4;
    constexpr int LBS = BN + 4;
    __shared__ float As[BK][LAS];
    __shared__ float Bs[BK][LBS];

    const int tid = threadIdx.x;
    const int bm  = blockIdx.y * BM;
    const int bn  = blockIdx.x * BN;
    const int tx  = tid % (BN/TN);
    const int ty  = tid / (BN/TN);

    float acc[TM][TN];
#pragma unroll
    for (int i=0;i<TM;i++)
#pragma unroll
        for (int j=0;j<TN;j++) acc[i][j]=0.f;

    for (int k0=0;k0<K;k0+=BK){
        // ---- load A tile (BM x BK), k-fastest float4, store transposed ----
        constexpr int A_IT = (BM*BK)/(NTH*4);
#pragma unroll
        for (int it=0; it<A_IT; ++it){
            const int idx = (tid + it*NTH)*4;
            const int m  = idx / BK;
            const int kk = idx % BK;
            const float4 v = *reinterpret_cast<const float4*>(A + (size_t)(bm+m)*lda + (k0+kk));
            As[kk+0][m]=v.x; As[kk+1][m]=v.y; As[kk+2][m]=v.z; As[kk+3][m]=v.w;
        }
        // ---- load B tile ----
        constexpr int B_IT = (BN*BK)/(NTH*4);
        if constexpr (BT){
#pragma unroll
            for (int it=0; it<B_IT; ++it){
                const int idx = (tid + it*NTH)*4;
                const int n  = idx / BK;
                const int kk = idx % BK;
                const float4 v = *reinterpret_cast<const float4*>(Bp + (size_t)(bn+n)*ldb + boff + (k0+kk));
                Bs[kk+0][n]=v.x; Bs[kk+1][n]=v.y; Bs[kk+2][n]=v.z; Bs[kk+3][n]=v.w;
            }
        } else {
#pragma unroll
            for (int it=0; it<B_IT; ++it){
                const int idx = (tid + it*NTH)*4;
                const int kk = idx / BN;
                const int n  = idx % BN;
                const float4 v = *reinterpret_cast<const float4*>(Bp + (size_t)(k0+kk)*ldb + (bn+n));
                *reinterpret_cast<float4*>(&Bs[kk][n]) = v;
            }
        }
        __syncthreads();

#pragma unroll
        for (int kk=0;kk<BK;kk++){
            float af[TM], bf[TN];
#pragma unroll
            for (int i=0;i<TM;i+=4){
                const float4 v = *reinterpret_cast<const float4*>(&As[kk][ty*TM+i]);
                af[i]=v.x; af[i+1]=v.y; af[i+2]=v.z; af[i+3]=v.w;
            }
#pragma unroll
            for (int j=0;j<TN;j+=4){
                const float4 v = *reinterpret_cast<const float4*>(&Bs[kk][tx*TN+j]);
                bf[j]=v.x; bf[j+1]=v.y; bf[j+2]=v.z; bf[j+3]=v.w;
            }
#pragma unroll
            for (int i=0;i<TM;i++)
#pragma unroll
                for (int j=0;j<TN;j++) acc[i][j] = fmaf(af[i], bf[j], acc[i][j]);
        }
        __syncthreads();
    }

    // ---- epilogue ----
#pragma unroll
    for (int i=0;i<TM;i++){
        const int m = bm + ty*TM + i;
#pragma unroll
        for (int j=0;j<TN;j+=4){
            const int n = bn + tx*TN + j;
            float4 c;
            c.x=acc[i][j]; c.y=acc[i][j+1]; c.z=acc[i][j+2]; c.w=acc[i][j+3];
            if constexpr (PRE){
                const float4 p = *reinterpret_cast<const float4*>(pre + (size_t)m*ldp + n);
                c.x+=p.x; c.y+=p.y; c.z+=p.z; c.w+=p.w;
            }
            if constexpr (BIAS){
                const float4 bv = *reinterpret_cast<const float4*>(bias + n);
                c.x+=bv.x; c.y+=bv.y; c.z+=bv.z; c.w+=bv.w;
            }
            if constexpr (EPI==1){ c.x=seluf_(c.x); c.y=seluf_(c.y); c.z=seluf_(c.z); c.w=seluf_(c.w); }
            else if constexpr (EPI==2){ c.x=fmaxf(c.x,0.f); c.y=fmaxf(c.y,0.f); c.z=fmaxf(c.z,0.f); c.w=fmaxf(c.w,0.f); }
            *reinterpret_cast<float4*>(C + (size_t)m*ldc + n) = c;
        }
    }
}

// ---------------------------------------------------------------------------
__global__ void init_xe_k(const float* __restrict__ x0, float* __restrict__ x_e){
    const int idx = blockIdx.x*256 + threadIdx.x;     // B_*E_ = 196608 exact
    x_e[idx] = x0[idx % E_];
}

__global__ void init_givec_k(const float* __restrict__ b0, const float* __restrict__ bWi,
                             const float* __restrict__ bbi, float* __restrict__ giv){
    const int j = blockIdx.x*256 + threadIdx.x;       // 3072 exact
    giv[j] = b0[0]*bWi[j] + bbi[j];
}

// beat GRU elementwise: gh already includes bh; giv already includes bi.
__global__ void beat_gru_ew(const float* __restrict__ gh, const float* __restrict__ giv,
                            float* __restrict__ h, float* __restrict__ beat_out, int s){
    const int idx = blockIdx.x*256 + threadIdx.x;     // B_*H_
    const int b = idx >> 10, j = idx & (H_-1);
    const size_t base = (size_t)b*H3_;
    const float ir = giv[j], iz = giv[H_+j], in = giv[2*H_+j];
    const float hr = gh[base+j], hz = gh[base+H_+j], hn = gh[base+2*H_+j];
    const float hv = h[idx];
    const float r = sigmoidf_(ir+hr);
    const float zg = sigmoidf_(iz+hz);
    const float n = tanhf(in + r*hn);
    const float hnew = (1.f-zg)*n + zg*hv;
    h[idx] = hnew;
    beat_out[(size_t)b*(BEATS_*H_) + (size_t)s*H_ + j] = hnew;
}

// tick GRU elementwise: gi = x@Wi.T + bi (full), gh = h@Wh.T + bh.
__global__ void tick_gru_ew(const float* __restrict__ gi, const float* __restrict__ gh,
                            float* __restrict__ h){
    const int idx = blockIdx.x*256 + threadIdx.x;     // B_*H_
    const int b = idx >> 10, j = idx & (H_-1);
    const size_t base = (size_t)b*H3_;
    const float ir = gi[base+j], iz = gi[base+H_+j], in = gi[base+2*H_+j];
    const float hr = gh[base+j], hz = gh[base+H_+j], hn = gh[base+2*H_+j];
    const float hv = h[idx];
    const float r = sigmoidf_(ir+hr);
    const float zg = sigmoidf_(iz+hz);
    const float n = tanhf(in + r*hn);
    h[idx] = (1.f-zg)*n + zg*hv;
}

// one wave per row: argmax over V (first-index tie-break), gather embedding, emit sample
__global__ void argmax_emb_k(const float* __restrict__ logits,   // d_out + col*V_, row stride 24*V_
                             const float* __restrict__ emb,
                             float* __restrict__ x_e,
                             float* __restrict__ samples){       // d_out + W0_ + col, row stride 24
    const int row  = blockIdx.x*4 + (threadIdx.x >> 6);
    const int lane = threadIdx.x & 63;
    const float* lr = logits + (size_t)row * (24*V_);
    float best = -1e30f; int bi = 0;
#pragma unroll
    for (int v0=0; v0<V_; v0+=64){
        const int v = v0 + lane;
        const float val = lr[v];
        if (val > best){ best = val; bi = v; }   // ascending v -> keeps first max in-lane
    }
#pragma unroll
    for (int off=32; off; off>>=1){
        const float ov = __shfl_xor(best, off);
        const int   oi = __shfl_xor(bi,  off);
        if (ov > best || (ov == best && oi < bi)){ best = ov; bi = oi; }
    }
    for (int k=lane; k<E_; k+=64)
        x_e[(size_t)row*E_ + k] = emb[(size_t)bi*E_ + k];
    if (lane == 0) samples[(size_t)row*24] = (float)bi;
}

// ---------------------------------------------------------------------------
extern "C" void kernel_launch(void* const* d_in, const int* in_sizes, int n_in,
                              void* d_out, int out_size, void* d_ws, size_t ws_size,
                              hipStream_t stream)
{
    const float* z    = (const float*)d_in[0];
    const float* emb  = (const float*)d_in[3];
    const float* z2W  = (const float*)d_in[4];
    const float* z2b  = (const float*)d_in[5];
    const float* b0   = (const float*)d_in[6];
    const float* bWi  = (const float*)d_in[7];
    const float* bWh  = (const float*)d_in[8];
    const float* bbi  = (const float*)d_in[9];
    const float* bbh  = (const float*)d_in[10];
    const float* hidW = (const float*)d_in[11];
    const float* hidb = (const float*)d_in[12];
    const float* inW  = (const float*)d_in[13];
    const float* inb  = (const float*)d_in[14];
    const float* x0   = (const float*)d_in[15];
    const float* tWi  = (const float*)d_in[16];
    const float* tWh  = (const float*)d_in[17];
    const float* tbi  = (const float*)d_in[18];
    const float* tbh  = (const float*)d_in[19];
    const float* outW = (const float*)d_in[20];
    const float* outb = (const float*)d_in[21];
    float* out = (float*)d_out;

    float* ws     = (float*)d_ws;
    float* ws_xe  = ws;                    // B*E          = 196608
    float* ws_giv = ws_xe  + B_*E_;        // 3072 (pad to 4096)
    float* ws_h   = ws_giv + 4096;         // B*H
    float* ws_bo  = ws_h   + (size_t)B_*H_;        // B*4*H
    float* ws_ht  = ws_bo  + (size_t)B_*BEATS_*H_; // B*H
    float* ws_be  = ws_ht  + (size_t)B_*H_;        // B*H
    float* ws_pre = ws_be  + (size_t)B_*H_;        // B*3H
    float* ws_gh  = ws_pre + (size_t)B_*H3_;       // B*3H
    float* ws_gi  = ws_gh  + (size_t)B_*H3_;       // B*3H   (total ~135 MB)

    const dim3 blk(256);
    const int ewGrid = (B_*H_)/256;

    // ---- init ----
    init_xe_k<<<(B_*E_)/256, blk, 0, stream>>>(x0, ws_xe);
    init_givec_k<<<H3_/256, blk, 0, stream>>>(b0, bWi, bbi, ws_giv);

    // ---- h_beat = selu(z @ z2W + z2b) -> ws_h ----
    gemm_k<128,128,16,8,8,0,1,1,0><<<dim3(H_/128, B_/128), blk, 0, stream>>>(
        z, ZD_, z2W, H_, 0, z2b, nullptr, 0, ws_h, H_, B_, H_, ZD_);

    // ---- beat GRU: 4 steps ----
    for (int s=0; s<BEATS_; ++s){
        gemm_k<128,128,16,8,8,1,0,1,0><<<dim3(H3_/128, B_/128), blk, 0, stream>>>(
            ws_h, H_, bWh, H_, 0, bbh, nullptr, 0, ws_gh, H3_, B_, H3_, H_);
        beat_gru_ew<<<ewGrid, blk, 0, stream>>>(ws_gh, ws_giv, ws_h, ws_bo, s);
    }

    // ---- beats ----
    for (int i=0; i<BEATS_; ++i){
        const float* ctx = ws_bo + (size_t)i*H_;   // row stride 4*H
        // h_tick = selu(ctx @ hidW + hidb)
        gemm_k<128,128,16,8,8,0,1,1,0><<<dim3(H_/128, B_/128), blk, 0, stream>>>(
            ctx, BEATS_*H_, hidW, H_, 0, hidb, nullptr, 0, ws_ht, H_, B_, H_, H_);
        // beat_emb = selu(ctx @ inW + inb)
        gemm_k<128,128,16,8,8,0,1,1,0><<<dim3(H_/128, B_/128), blk, 0, stream>>>(
            ctx, BEATS_*H_, inW, H_, 0, inb, nullptr, 0, ws_be, H_, B_, H_, H_);
        // pre = beat_emb @ tWi[:,96:].T + tbi
        gemm_k<128,128,16,8,8,1,0,1,0><<<dim3(H3_/128, B_/128), blk, 0, stream>>>(
            ws_be, H_, tWi, E_+H_, E_, tbi, nullptr, 0, ws_pre, H3_, B_, H3_, H_);

        for (int t=0; t<TICKS_; ++t){
            const int col = i*TICKS_ + t;
            // gh = h @ tWh.T + tbh
            gemm_k<128,128,16,8,8,1,0,1,0><<<dim3(H3_/128, B_/128), blk, 0, stream>>>(
                ws_ht, H_, tWh, H_, 0, tbh, nullptr, 0, ws_gh, H3_, B_, H3_, H_);
            // gi = x_e @ tWi[:,:96].T + pre
            gemm_k<128,128,16,8,8,1,0,0,1><<<dim3(H3_/128, B_/128), blk, 0, stream>>>(
                ws_xe, E_, tWi, E_+H_, 0, nullptr, ws_pre, H3_, ws_gi, H3_, B_, H3_, E_);
            // GRU update
            tick_gru_ew<<<ewGrid, blk, 0, stream>>>(ws_gi, ws_gh, ws_ht);
            // logits = relu(h @ outW + outb) -> d_out block
            gemm_k<64,64,16,4,4,0,2,1,0><<<dim3(V_/64, B_/64), blk, 0, stream>>>(
                ws_ht, H_, outW, V_, 0, outb, nullptr, 0, out + (size_t)col*V_, 24*V_, B_, V_, H_);
            // argmax + embedding gather + sample
            argmax_emb_k<<<B_/4, blk, 0, stream>>>(out + (size_t)col*V_, emb, ws_xe,
                                                   out + W0_ + col);
        }
    }
    (void)in_sizes; (void)n_in; (void)out_size; (void)ws_size;
}

// Round 2
// 3193.103 us; speedup vs baseline: 2.9505x; 2.9505x over previous
//
#include <hip/hip_runtime.h>
#include <hip/hip_fp16.h>
#include <math.h>
#include <stdint.h>

#define B_     2048
#define ZD_    256
#define H_     1024
#define E_     96
#define V_     512
#define BEATS_ 4
#define TICKS_ 6
#define H3_    3072
#define W0_    25165824UL   // B*24*V, start of samples section in d_out

typedef _Float16 f16x8 __attribute__((ext_vector_type(8)));
typedef float    f32x4 __attribute__((ext_vector_type(4)));

__device__ __forceinline__ float sigmoidf_(float x){ return 1.f/(1.f+expf(-x)); }
__device__ __forceinline__ float seluf_(float x){
    const float a = 1.6732632423543772f, s = 1.0507009873554805f;
    return x > 0.f ? s*x : s*a*expm1f(x);
}

// fragment-major (16 rows x 8 k) layout offset, in elements. KD = K-dim size (mult of 8).
__device__ __forceinline__ size_t fragoff(int r, int k, int KD){
    return ((size_t)(r>>4)*(KD>>3) + (k>>3))*128 + (size_t)((r&15)<<3) + (k&7);
}

__device__ __forceinline__ void store_pl(_Float16* __restrict__ hi, _Float16* __restrict__ lo,
                                         size_t off, float x){
    _Float16 h = (_Float16)x;
    hi[off] = h;
    lo[off] = (_Float16)((x - (float)h) * 2048.f);
}

__device__ __forceinline__ void gload16(const void* g, void* l){
    __builtin_amdgcn_global_load_lds(
        (const __attribute__((address_space(1))) uint32_t*)g,
        (__attribute__((address_space(3))) uint32_t*)l,
        16, 0, 0);
}

// ---------------------------------------------------------------------------
// fp32 -> (hi,lo) fp16 planes in fragment-major layout.
// T=0: logical (r,k) = src[r*ld + k].  T=1: (r,k) = src[k*ld + r] (transpose).
// ---------------------------------------------------------------------------
template<int T>
__global__ void cvt_pl(const float* __restrict__ src, int ld,
                       _Float16* __restrict__ hi, _Float16* __restrict__ lo,
                       int NR, int NK){
    const int idx = blockIdx.x*256 + threadIdx.x;
    if (idx >= NR*NK) return;
    const int r = idx / NK, k = idx - r*NK;
    const float x = T ? src[(size_t)k*ld + r] : src[(size_t)r*ld + k];
    store_pl(hi, lo, fragoff(r, k, NK), x);
}

// ---------------------------------------------------------------------------
// MFMA fp16x2-split GEMM: C[M,N] = act( sum_k A[m,k]*B[n,k] + bias[n] + pre[m,n] )
// A,B are (hi,lo) plane pairs in fragment-major layout with K-dims KA,KB.
// B k-window starts at kb0 (mult of 32). Tile 128x64, BK=32, 4 waves (64x32 each).
// Grid: (N/64, M/128). K mult of 32, M mult of 128, N mult of 64.
// ---------------------------------------------------------------------------
template<int EPI,int BIAS,int PRE,int WRITEC,int WRITEP>
__global__ __launch_bounds__(256,2)
void mgemm(const _Float16* __restrict__ Ahp, const _Float16* __restrict__ Alp, int KA,
           const _Float16* __restrict__ Bhp, const _Float16* __restrict__ Blp, int KB, int kb0,
           const float* __restrict__ bias,
           const float* __restrict__ pre, int ldp,
           float* __restrict__ C, long ldc,
           _Float16* __restrict__ Chp, _Float16* __restrict__ Clp, int KC,
           int K)
{
    __shared__ __align__(16) _Float16 Asm[2][128*32];
    __shared__ __align__(16) _Float16 Bsm[2][64*32];

    const int tid  = threadIdx.x;
    const int lane = tid & 63;
    const int w    = tid >> 6;
    const int wm   = w >> 1, wn = w & 1;
    const int bm   = blockIdx.y * 128, bn = blockIdx.x * 64;

    f32x4 acc0[4][2], acc1[4][2];
#pragma unroll
    for (int i=0;i<4;i++)
#pragma unroll
        for (int j=0;j<2;j++){ acc0[i][j]=(f32x4)0.f; acc1[i][j]=(f32x4)0.f; }

    const int kgA = KA >> 3, kgB = KB >> 3;
    const int lro = ((lane>>4)<<7) + ((lane&15)<<3);   // kg*128 + r*8

    for (int k0 = 0; k0 < K; k0 += 32){
        // ---- stage: 24 wave-issues of 1KB each (A: 8rb x 2pl, B: 4rb x 2pl) ----
#pragma unroll
        for (int tt = 0; tt < 6; ++tt){
            const int t = w + tt*4;
            const _Float16* g; _Float16* dst;
            if (t < 16){
                const int p = t >> 3, rb = t & 7;
                const _Float16* base = p ? Alp : Ahp;
                g   = base + ((size_t)((bm>>4)+rb)*kgA + (k0>>3))*128;
                dst = &Asm[p][rb*512];
            } else {
                const int u = t - 16, p = u >> 2, rb = u & 3;
                const _Float16* base = p ? Blp : Bhp;
                g   = base + ((size_t)((bn>>4)+rb)*kgB + ((kb0+k0)>>3))*128;
                dst = &Bsm[p][rb*512];
            }
            gload16(g + lane*8, dst);
        }
        __syncthreads();

        f16x8 ah[4], al[4], bh[2], bl[2];
#pragma unroll
        for (int fr=0; fr<4; ++fr){
            ah[fr] = *(const f16x8*)&Asm[0][(wm*4+fr)*512 + lro];
            al[fr] = *(const f16x8*)&Asm[1][(wm*4+fr)*512 + lro];
        }
#pragma unroll
        for (int fn=0; fn<2; ++fn){
            bh[fn] = *(const f16x8*)&Bsm[0][(wn*2+fn)*512 + lro];
            bl[fn] = *(const f16x8*)&Bsm[1][(wn*2+fn)*512 + lro];
        }
#pragma unroll
        for (int fr=0; fr<4; ++fr)
#pragma unroll
        for (int fn=0; fn<2; ++fn){
            acc0[fr][fn] = __builtin_amdgcn_mfma_f32_16x16x32_f16(ah[fr], bh[fn], acc0[fr][fn],0,0,0);
            acc1[fr][fn] = __builtin_amdgcn_mfma_f32_16x16x32_f16(ah[fr], bl[fn], acc1[fr][fn],0,0,0);
            acc1[fr][fn] = __builtin_amdgcn_mfma_f32_16x16x32_f16(al[fr], bh[fn], acc1[fr][fn],0,0,0);
        }
        __syncthreads();
    }

    // ---- epilogue: C/D frag mapping col=lane&15, row=(lane>>4)*4+q ----
    const int rq = (lane>>4)<<2;
    const int cn = lane & 15;
#pragma unroll
    for (int fr=0; fr<4; ++fr){
        const int m0 = bm + wm*64 + fr*16 + rq;
#pragma unroll
        for (int fn=0; fn<2; ++fn){
            const int n = bn + wn*32 + fn*16 + cn;
#pragma unroll
            for (int q=0; q<4; ++q){
                const int m = m0 + q;
                float v = acc0[fr][fn][q] + acc1[fr][fn][q]*(1.0f/2048.0f);
                if constexpr(PRE)  v += pre[(size_t)m*ldp + n];
                if constexpr(BIAS) v += bias[n];
                if constexpr(EPI==1) v = seluf_(v);
                else if constexpr(EPI==2) v = fmaxf(v, 0.f);
                if constexpr(WRITEC) C[(size_t)m*ldc + n] = v;
                if constexpr(WRITEP) store_pl(Chp, Clp, fragoff(m, n, KC), v);
            }
        }
    }
}

// ---------------------------------------------------------------------------
__global__ void init_xepl_k(const float* __restrict__ x0,
                            _Float16* __restrict__ xh, _Float16* __restrict__ xl){
    const int idx = blockIdx.x*256 + threadIdx.x;
    if (idx >= B_*E_) return;
    const int r = idx / E_, k = idx - r*E_;
    store_pl(xh, xl, fragoff(r, k, E_), x0[k]);
}

__global__ void init_givec_k(const float* __restrict__ b0, const float* __restrict__ bWi,
                             const float* __restrict__ bbi, float* __restrict__ giv){
    const int j = blockIdx.x*256 + threadIdx.x;       // 3072 exact
    giv[j] = b0[0]*bWi[j] + bbi[j];
}

// beat GRU elementwise; writes fp32 h, h-planes, and ctx-planes (beat_out slot)
__global__ void beat_gru_ew(const float* __restrict__ gh, const float* __restrict__ giv,
                            float* __restrict__ h,
                            _Float16* __restrict__ hh, _Float16* __restrict__ hl,
                            _Float16* __restrict__ ch, _Float16* __restrict__ cl){
    const int idx = blockIdx.x*256 + threadIdx.x;     // B_*H_
    const int b = idx >> 10, j = idx & (H_-1);
    const size_t base = (size_t)b*H3_;
    const float ir = giv[j], iz = giv[H_+j], in = giv[2*H_+j];
    const float hr = gh[base+j], hz = gh[base+H_+j], hn = gh[base+2*H_+j];
    const float hv = h[idx];
    const float r  = sigmoidf_(ir+hr);
    const float zg = sigmoidf_(iz+hz);
    const float n  = tanhf(in + r*hn);
    const float hnew = (1.f-zg)*n + zg*hv;
    h[idx] = hnew;
    const size_t off = fragoff(b, j, H_);
    _Float16 vh = (_Float16)hnew;
    _Float16 vl = (_Float16)((hnew - (float)vh)*2048.f);
    hh[off]=vh; hl[off]=vl; ch[off]=vh; cl[off]=vl;
}

// tick GRU elementwise; writes fp32 h and h-planes
__global__ void tick_gru_ew(const float* __restrict__ gi, const float* __restrict__ gh,
                            float* __restrict__ h,
                            _Float16* __restrict__ hh, _Float16* __restrict__ hl){
    const int idx = blockIdx.x*256 + threadIdx.x;     // B_*H_
    const int b = idx >> 10, j = idx & (H_-1);
    const size_t base = (size_t)b*H3_;
    const float ir = gi[base+j], iz = gi[base+H_+j], in = gi[base+2*H_+j];
    const float hr = gh[base+j], hz = gh[base+H_+j], hn = gh[base+2*H_+j];
    const float hv = h[idx];
    const float r  = sigmoidf_(ir+hr);
    const float zg = sigmoidf_(iz+hz);
    const float n  = tanhf(in + r*hn);
    const float hnew = (1.f-zg)*n + zg*hv;
    h[idx] = hnew;
    store_pl(hh, hl, fragoff(b, j, H_), hnew);
}

// one wave per row: argmax over V (first-index tie-break), gather embedding -> xe planes
__global__ void argmax_emb_k(const float* __restrict__ logits,   // row stride 24*V_
                             const float* __restrict__ emb,
                             _Float16* __restrict__ xh, _Float16* __restrict__ xl,
                             float* __restrict__ samples){       // row stride 24
    const int row  = blockIdx.x*4 + (threadIdx.x >> 6);
    const int lane = threadIdx.x & 63;
    const float* lr = logits + (size_t)row * (24*V_);
    float best = -1e30f; int bi = 0;
#pragma unroll
    for (int v0=0; v0<V_; v0+=64){
        const int v = v0 + lane;
        const float val = lr[v];
        if (val > best){ best = val; bi = v; }   // ascending v -> keeps first max in-lane
    }
#pragma unroll
    for (int off=32; off; off>>=1){
        const float ov = __shfl_xor(best, off);
        const int   oi = __shfl_xor(bi,  off);
        if (ov > best || (ov == best && oi < bi)){ best = ov; bi = oi; }
    }
    for (int k=lane; k<E_; k+=64)
        store_pl(xh, xl, fragoff(row, k, E_), emb[(size_t)bi*E_ + k]);
    if (lane == 0) samples[(size_t)row*24] = (float)bi;
}

// ---------------------------------------------------------------------------
extern "C" void kernel_launch(void* const* d_in, const int* in_sizes, int n_in,
                              void* d_out, int out_size, void* d_ws, size_t ws_size,
                              hipStream_t stream)
{
    const float* z    = (const float*)d_in[0];
    const float* emb  = (const float*)d_in[3];
    const float* z2W  = (const float*)d_in[4];
    const float* z2b  = (const float*)d_in[5];
    const float* b0   = (const float*)d_in[6];
    const float* bWi  = (const float*)d_in[7];
    const float* bWh  = (const float*)d_in[8];
    const float* bbi  = (const float*)d_in[9];
    const float* bbh  = (const float*)d_in[10];
    const float* hidW = (const float*)d_in[11];
    const float* hidb = (const float*)d_in[12];
    const float* inW  = (const float*)d_in[13];
    const float* inb  = (const float*)d_in[14];
    const float* x0   = (const float*)d_in[15];
    const float* tWi  = (const float*)d_in[16];
    const float* tWh  = (const float*)d_in[17];
    const float* tbi  = (const float*)d_in[18];
    const float* tbh  = (const float*)d_in[19];
    const float* outW = (const float*)d_in[20];
    const float* outb = (const float*)d_in[21];
    float* out = (float*)d_out;

    // ---- workspace carve (bytes) ----
    char* p = (char*)d_ws;
    auto alloc_f = [&](size_t n){ float*    r = (float*)p;    p += n*4; return r; };
    auto alloc_h = [&](size_t n){ _Float16* r = (_Float16*)p; p += n*2; return r; };

    float* giv    = alloc_f(4096);
    float* ws_h   = alloc_f((size_t)B_*H_);     // beat-phase h (fp32)
    float* ws_ht  = alloc_f((size_t)B_*H_);     // tick-phase h (fp32)
    float* ws_pre = alloc_f((size_t)B_*H3_);
    float* ws_gh  = alloc_f((size_t)B_*H3_);
    float* ws_gi  = alloc_f((size_t)B_*H3_);

    _Float16 *hplh  = alloc_h((size_t)B_*H_),  *hpll  = alloc_h((size_t)B_*H_);
    _Float16 *beplh = alloc_h((size_t)B_*H_),  *bepll = alloc_h((size_t)B_*H_);
    _Float16 *ctxh[BEATS_], *ctxl[BEATS_];
    for (int i=0;i<BEATS_;i++){ ctxh[i]=alloc_h((size_t)B_*H_); ctxl[i]=alloc_h((size_t)B_*H_); }
    _Float16 *xeh   = alloc_h((size_t)B_*E_),  *xel   = alloc_h((size_t)B_*E_);
    _Float16 *zh    = alloc_h((size_t)B_*ZD_), *zl    = alloc_h((size_t)B_*ZD_);
    _Float16 *z2Wh  = alloc_h((size_t)H_*ZD_), *z2Wl  = alloc_h((size_t)H_*ZD_);
    _Float16 *bWhh  = alloc_h((size_t)H3_*H_), *bWhl  = alloc_h((size_t)H3_*H_);
    _Float16 *hidWh = alloc_h((size_t)H_*H_),  *hidWl = alloc_h((size_t)H_*H_);
    _Float16 *inWh  = alloc_h((size_t)H_*H_),  *inWl  = alloc_h((size_t)H_*H_);
    _Float16 *tWih  = alloc_h((size_t)H3_*(E_+H_)), *tWil = alloc_h((size_t)H3_*(E_+H_));
    _Float16 *tWhh  = alloc_h((size_t)H3_*H_), *tWhl  = alloc_h((size_t)H3_*H_);
    _Float16 *outWh = alloc_h((size_t)V_*H_),  *outWl = alloc_h((size_t)V_*H_);

    const dim3 blk(256);
    auto G1 = [](long n){ return dim3((unsigned)((n+255)/256)); };
    const int ewGrid = (B_*H_)/256;

    // ---- one-time conversions to fragment-major fp16x2 planes ----
    cvt_pl<0><<<G1((long)B_*ZD_),  blk,0,stream>>>(z,    ZD_,   zh,    zl,    B_,  ZD_);
    cvt_pl<1><<<G1((long)H_*ZD_),  blk,0,stream>>>(z2W,  H_,    z2Wh,  z2Wl,  H_,  ZD_);   // (n,k)=src[k*H_+n]
    cvt_pl<0><<<G1((long)H3_*H_),  blk,0,stream>>>(bWh,  H_,    bWhh,  bWhl,  H3_, H_);
    cvt_pl<1><<<G1((long)H_*H_),   blk,0,stream>>>(hidW, H_,    hidWh, hidWl, H_,  H_);
    cvt_pl<1><<<G1((long)H_*H_),   blk,0,stream>>>(inW,  H_,    inWh,  inWl,  H_,  H_);
    cvt_pl<0><<<G1((long)H3_*(E_+H_)),blk,0,stream>>>(tWi, E_+H_, tWih, tWil, H3_, E_+H_);
    cvt_pl<0><<<G1((long)H3_*H_),  blk,0,stream>>>(tWh,  H_,    tWhh,  tWhl,  H3_, H_);
    cvt_pl<1><<<G1((long)H_*V_),   blk,0,stream>>>(outW, V_,    outWh, outWl, V_,  H_);

    init_xepl_k<<<G1((long)B_*E_), blk,0,stream>>>(x0, xeh, xel);
    init_givec_k<<<H3_/256, blk,0,stream>>>(b0, bWi, bbi, giv);

    // ---- h_beat = selu(z @ z2W + z2b): fp32 -> ws_h, planes -> hpl ----
    mgemm<1,1,0,1,1><<<dim3(H_/64, B_/128), blk,0,stream>>>(
        zh, zl, ZD_, z2Wh, z2Wl, ZD_, 0, z2b, nullptr,0,
        ws_h, H_, hplh, hpll, H_, ZD_);

    // ---- beat GRU: 4 steps ----
    for (int s=0; s<BEATS_; ++s){
        mgemm<0,1,0,1,0><<<dim3(H3_/64, B_/128), blk,0,stream>>>(
            hplh, hpll, H_, bWhh, bWhl, H_, 0, bbh, nullptr,0,
            ws_gh, H3_, nullptr,nullptr,0, H_);
        beat_gru_ew<<<ewGrid, blk,0,stream>>>(ws_gh, giv, ws_h, hplh, hpll, ctxh[s], ctxl[s]);
    }

    // ---- beats ----
    for (int i=0; i<BEATS_; ++i){
        // h_tick = selu(ctx @ hidW + hidb): fp32 -> ws_ht, planes -> hpl
        mgemm<1,1,0,1,1><<<dim3(H_/64, B_/128), blk,0,stream>>>(
            ctxh[i], ctxl[i], H_, hidWh, hidWl, H_, 0, hidb, nullptr,0,
            ws_ht, H_, hplh, hpll, H_, H_);
        // beat_emb = selu(ctx @ inW + inb): planes only
        mgemm<1,1,0,0,1><<<dim3(H_/64, B_/128), blk,0,stream>>>(
            ctxh[i], ctxl[i], H_, inWh, inWl, H_, 0, inb, nullptr,0,
            nullptr, 0, beplh, bepll, H_, H_);
        // pre = beat_emb @ tWi[:,96:].T + tbi  (fp32)
        mgemm<0,1,0,1,0><<<dim3(H3_/64, B_/128), blk,0,stream>>>(
            beplh, bepll, H_, tWih, tWil, E_+H_, E_, tbi, nullptr,0,
            ws_pre, H3_, nullptr,nullptr,0, H_);

        for (int t=0; t<TICKS_; ++t){
            const int col = i*TICKS_ + t;
            // gh = h @ tWh.T + tbh
            mgemm<0,1,0,1,0><<<dim3(H3_/64, B_/128), blk,0,stream>>>(
                hplh, hpll, H_, tWhh, tWhl, H_, 0, tbh, nullptr,0,
                ws_gh, H3_, nullptr,nullptr,0, H_);
            // gi = x_e @ tWi[:,:96].T + pre
            mgemm<0,0,1,1,0><<<dim3(H3_/64, B_/128), blk,0,stream>>>(
                xeh, xel, E_, tWih, tWil, E_+H_, 0, nullptr, ws_pre, H3_,
                ws_gi, H3_, nullptr,nullptr,0, E_);
            // GRU update (fp32 h + planes)
            tick_gru_ew<<<ewGrid, blk,0,stream>>>(ws_gi, ws_gh, ws_ht, hplh, hpll);
            // logits = relu(h @ outW + outb) -> d_out block
            mgemm<2,1,0,1,0><<<dim3(V_/64, B_/128), blk,0,stream>>>(
                hplh, hpll, H_, outWh, outWl, H_, 0, outb, nullptr,0,
                out + (size_t)col*V_, 24*V_, nullptr,nullptr,0, H_);
            // argmax + embedding gather (writes xe planes) + sample
            argmax_emb_k<<<B_/4, blk,0,stream>>>(out + (size_t)col*V_, emb,
                                                 xeh, xel, out + W0_ + col);
        }
    }
    (void)in_sizes; (void)n_in; (void)out_size; (void)ws_size;
}

// Round 3
// 2515.962 us; speedup vs baseline: 3.7445x; 1.2691x over previous
//
#include <hip/hip_runtime.h>
#include <hip/hip_fp16.h>
#include <math.h>
#include <stdint.h>

#define B_     2048
#define ZD_    256
#define H_     1024
#define E_     96
#define V_     512
#define BEATS_ 4
#define TICKS_ 6
#define H3_    3072
#define KXT_   1120            // 1024 (h) + 96 (x_e) merged K for tick GRU
#define W0_    25165824UL      // B*24*V, start of samples section in d_out
#define INV2K_ 4.8828125e-4f   // 1/2048

typedef _Float16 f16x8 __attribute__((ext_vector_type(8)));
typedef float    f32x4 __attribute__((ext_vector_type(4)));

__device__ __forceinline__ float sigmoidf_(float x){ return 1.f/(1.f+expf(-x)); }
__device__ __forceinline__ float seluf_(float x){
    const float a = 1.6732632423543772f, s = 1.0507009873554805f;
    return x > 0.f ? s*x : s*a*expm1f(x);
}

// fragment-major (16 rows x 8 k) layout offset, in elements. KD mult of 8.
__device__ __forceinline__ size_t fragoff(int r, int k, int KD){
    return ((size_t)(r>>4)*(KD>>3) + (k>>3))*128 + (size_t)((r&15)<<3) + (k&7);
}

__device__ __forceinline__ void store_pl(_Float16* __restrict__ hi, _Float16* __restrict__ lo,
                                         size_t off, float x){
    _Float16 h = (_Float16)x;
    hi[off] = h;
    lo[off] = (_Float16)((x - (float)h) * 2048.f);
}

__device__ __forceinline__ void gload16(const void* g, void* l){
    __builtin_amdgcn_global_load_lds(
        (const __attribute__((address_space(1))) uint32_t*)g,
        (__attribute__((address_space(3))) uint32_t*)l,
        16, 0, 0);
}

// ---------------------------------------------------------------------------
// fp32 -> (hi,lo) fp16 planes, fragment-major. T=1 transposes src.
// ---------------------------------------------------------------------------
template<int T>
__global__ void cvt_pl(const float* __restrict__ src, int ld,
                       _Float16* __restrict__ hi, _Float16* __restrict__ lo,
                       int NR, int NK){
    const int idx = blockIdx.x*256 + threadIdx.x;
    if (idx >= NR*NK) return;
    const int r = idx / NK, k = idx - r*NK;
    const float x = T ? src[(size_t)k*ld + r] : src[(size_t)r*ld + k];
    store_pl(hi, lo, fragoff(r, k, NK), x);
}

// ---------------------------------------------------------------------------
// MFMA fp16x2-split GEMM: C[M,N] = act( sum_k A[m,k]*B[n,k] + bias[n] )
// Tile BM x BN, BK=32, 4 waves (2x2). Grid (N/BN, M/BM).
// ---------------------------------------------------------------------------
template<int BM,int BN,int EPI,int BIAS,int WRITEC,int WRITEP>
__global__ __launch_bounds__(256,2)
void mgemm(const _Float16* __restrict__ Ahp, const _Float16* __restrict__ Alp, int KA,
           const _Float16* __restrict__ Bhp, const _Float16* __restrict__ Blp, int KB, int kb0,
           const float* __restrict__ bias,
           float* __restrict__ C, long ldc,
           _Float16* __restrict__ Chp, _Float16* __restrict__ Clp, int KC,
           int K)
{
    constexpr int FR  = BM/32, FN = BN/32;
    constexpr int ARB = BM/16, BRB = BN/16;
    constexpr int TOT = (BM+BN)/8;   // 1KB wave-issues per K-step
    __shared__ __align__(16) _Float16 Asm[2][BM*32];
    __shared__ __align__(16) _Float16 Bsm[2][BN*32];

    const int tid  = threadIdx.x;
    const int lane = tid & 63;
    const int w    = tid >> 6;
    const int wm   = w >> 1, wn = w & 1;
    const int bm   = blockIdx.y * BM, bn = blockIdx.x * BN;
    const int kgA  = KA >> 3, kgB = KB >> 3;
    const int lro  = ((lane>>4)<<7) + ((lane&15)<<3);

    f32x4 acc0[FR][FN], acc1[FR][FN];
#pragma unroll
    for (int i=0;i<FR;i++)
#pragma unroll
        for (int j=0;j<FN;j++){ acc0[i][j]=(f32x4)0.f; acc1[i][j]=(f32x4)0.f; }

    for (int k0 = 0; k0 < K; k0 += 32){
#pragma unroll
        for (int tt = 0; tt < TOT/4; ++tt){
            const int t = w + tt*4;
            const _Float16* g; _Float16* dst;
            if (t < ARB*2){
                const int p = t/ARB, rb = t%ARB;
                g   = (p ? Alp : Ahp) + ((size_t)((bm>>4)+rb)*kgA + (k0>>3))*128;
                dst = &Asm[p][rb*512];
            } else {
                const int u = t - ARB*2;
                const int p = u/BRB, rb = u%BRB;
                g   = (p ? Blp : Bhp) + ((size_t)((bn>>4)+rb)*kgB + ((kb0+k0)>>3))*128;
                dst = &Bsm[p][rb*512];
            }
            gload16(g + lane*8, dst);
        }
        __syncthreads();

        f16x8 ah[FR], al[FR], bh[FN], bl[FN];
#pragma unroll
        for (int fr=0; fr<FR; ++fr){
            ah[fr] = *(const f16x8*)&Asm[0][(wm*FR+fr)*512 + lro];
            al[fr] = *(const f16x8*)&Asm[1][(wm*FR+fr)*512 + lro];
        }
#pragma unroll
        for (int fn=0; fn<FN; ++fn){
            bh[fn] = *(const f16x8*)&Bsm[0][(wn*FN+fn)*512 + lro];
            bl[fn] = *(const f16x8*)&Bsm[1][(wn*FN+fn)*512 + lro];
        }
#pragma unroll
        for (int fr=0; fr<FR; ++fr)
#pragma unroll
        for (int fn=0; fn<FN; ++fn){
            acc0[fr][fn] = __builtin_amdgcn_mfma_f32_16x16x32_f16(ah[fr], bh[fn], acc0[fr][fn],0,0,0);
            acc1[fr][fn] = __builtin_amdgcn_mfma_f32_16x16x32_f16(ah[fr], bl[fn], acc1[fr][fn],0,0,0);
            acc1[fr][fn] = __builtin_amdgcn_mfma_f32_16x16x32_f16(al[fr], bh[fn], acc1[fr][fn],0,0,0);
        }
        __syncthreads();
    }

    const int rq = (lane>>4)<<2;
    const int cn = lane & 15;
#pragma unroll
    for (int fr=0; fr<FR; ++fr){
        const int m0 = bm + wm*(BM/2) + fr*16 + rq;
#pragma unroll
        for (int fn=0; fn<FN; ++fn){
            const int n = bn + wn*(BN/2) + fn*16 + cn;
#pragma unroll
            for (int q=0; q<4; ++q){
                const int m = m0 + q;
                float v = acc0[fr][fn][q] + acc1[fr][fn][q]*INV2K_;
                if constexpr(BIAS) v += bias[n];
                if constexpr(EPI==1) v = seluf_(v);
                else if constexpr(EPI==2) v = fmaxf(v, 0.f);
                if constexpr(WRITEC) C[(size_t)m*ldc + n] = v;
                if constexpr(WRITEP) store_pl(Chp, Clp, fragoff(m, n, KC), v);
            }
        }
    }
}

// ---------------------------------------------------------------------------
// Fused GRU GEMM+epilogue. Block: 128 batch-rows x 32 j-cols x 3 gates.
// A = h planes (KD = 1024 or 1120 with x_e at k>=1024). Wh planes KD=1024.
// HASX: x-region K steps use Wi planes (KD=1120, cols [0,96)); n-gate x-part
// goes to separate accumulators (n = tanh(i_n + r*h_n)).
// PREVEC: gi precomputed as vector prev[3072] (beat). Else matrix prev[m][3072].
// Epilogue: full GRU update; writes hnew planes to (Nh,Nl) [+ ctx (Ch,Cl)].
// ---------------------------------------------------------------------------
template<int PREVEC,int HASX,int WRITECTX>
__global__ __launch_bounds__(256,2)
void gru_gemm(const _Float16* __restrict__ Ahp, const _Float16* __restrict__ Alp, int KD,
              const _Float16* __restrict__ Whh, const _Float16* __restrict__ Whl,
              const _Float16* __restrict__ Wih, const _Float16* __restrict__ Wil,
              const float* __restrict__ prev,
              const float* __restrict__ bh,
              _Float16* __restrict__ Nh, _Float16* __restrict__ Nl,
              _Float16* __restrict__ Ch, _Float16* __restrict__ Cl)
{
    __shared__ __align__(16) _Float16 Asm[2][128*32];
    __shared__ __align__(16) _Float16 Bsm[2][96*32];

    const int tid  = threadIdx.x;
    const int lane = tid & 63;
    const int w    = tid >> 6;
    const int wm   = w >> 1, wn = w & 1;
    const int bm   = blockIdx.y * 128, jb = blockIdx.x * 32;
    const int kgA  = KD >> 3;
    const int lro  = ((lane>>4)<<7) + ((lane&15)<<3);

    f32x4 a0[4][3], a1[4][3];
#pragma unroll
    for (int i=0;i<4;i++)
#pragma unroll
        for (int g=0;g<3;g++){ a0[i][g]=(f32x4)0.f; a1[i][g]=(f32x4)0.f; }
    f32x4 x0v[4], x1v[4];
    if constexpr(HASX){
#pragma unroll
        for (int i=0;i<4;i++){ x0v[i]=(f32x4)0.f; x1v[i]=(f32x4)0.f; }
    }

    // ---- main K region (h part, K=1024, B from Wh planes, kgB=128) ----
    for (int k0 = 0; k0 < 1024; k0 += 32){
#pragma unroll
        for (int tt = 0; tt < 7; ++tt){
            const int t = w + tt*4;
            const _Float16* g; _Float16* dst;
            if (t < 16){
                const int p = t>>3, rb = t&7;
                g   = (p ? Alp : Ahp) + ((size_t)((bm>>4)+rb)*kgA + (k0>>3))*128;
                dst = &Asm[p][rb*512];
            } else {
                const int u = t-16, p = u/6, rb = u%6;
                const int gg = rb>>1, half = rb&1;
                g   = (p ? Whl : Whh) + ((size_t)(gg*64 + (jb>>4) + half)*128 + (k0>>3))*128;
                dst = &Bsm[p][rb*512];
            }
            gload16(g + lane*8, dst);
        }
        __syncthreads();

        f16x8 ah[4], al[4];
#pragma unroll
        for (int fr=0; fr<4; ++fr){
            ah[fr] = *(const f16x8*)&Asm[0][(wm*4+fr)*512 + lro];
            al[fr] = *(const f16x8*)&Asm[1][(wm*4+fr)*512 + lro];
        }
#pragma unroll
        for (int g=0; g<3; ++g){
            const f16x8 bhv = *(const f16x8*)&Bsm[0][(g*2+wn)*512 + lro];
            const f16x8 blv = *(const f16x8*)&Bsm[1][(g*2+wn)*512 + lro];
#pragma unroll
            for (int fr=0; fr<4; ++fr){
                a0[fr][g] = __builtin_amdgcn_mfma_f32_16x16x32_f16(ah[fr], bhv, a0[fr][g],0,0,0);
                a1[fr][g] = __builtin_amdgcn_mfma_f32_16x16x32_f16(ah[fr], blv, a1[fr][g],0,0,0);
                a1[fr][g] = __builtin_amdgcn_mfma_f32_16x16x32_f16(al[fr], bhv, a1[fr][g],0,0,0);
            }
        }
        __syncthreads();
    }

    // ---- x region (x_e part, K=96, B from Wi planes cols [0,96), kgB=140) ----
    if constexpr(HASX){
        for (int s = 0; s < 3; ++s){
            const int k0 = 1024 + s*32;
#pragma unroll
            for (int tt = 0; tt < 7; ++tt){
                const int t = w + tt*4;
                const _Float16* g; _Float16* dst;
                if (t < 16){
                    const int p = t>>3, rb = t&7;
                    g   = (p ? Alp : Ahp) + ((size_t)((bm>>4)+rb)*kgA + (k0>>3))*128;
                    dst = &Asm[p][rb*512];
                } else {
                    const int u = t-16, p = u/6, rb = u%6;
                    const int gg = rb>>1, half = rb&1;
                    g   = (p ? Wil : Wih) + ((size_t)(gg*64 + (jb>>4) + half)*140 + s*4)*128;
                    dst = &Bsm[p][rb*512];
                }
                gload16(g + lane*8, dst);
            }
            __syncthreads();

            f16x8 ah[4], al[4];
#pragma unroll
            for (int fr=0; fr<4; ++fr){
                ah[fr] = *(const f16x8*)&Asm[0][(wm*4+fr)*512 + lro];
                al[fr] = *(const f16x8*)&Asm[1][(wm*4+fr)*512 + lro];
            }
#pragma unroll
            for (int g=0; g<3; ++g){
                const f16x8 bhv = *(const f16x8*)&Bsm[0][(g*2+wn)*512 + lro];
                const f16x8 blv = *(const f16x8*)&Bsm[1][(g*2+wn)*512 + lro];
#pragma unroll
                for (int fr=0; fr<4; ++fr){
                    if (g < 2){
                        a0[fr][g] = __builtin_amdgcn_mfma_f32_16x16x32_f16(ah[fr], bhv, a0[fr][g],0,0,0);
                        a1[fr][g] = __builtin_amdgcn_mfma_f32_16x16x32_f16(ah[fr], blv, a1[fr][g],0,0,0);
                        a1[fr][g] = __builtin_amdgcn_mfma_f32_16x16x32_f16(al[fr], bhv, a1[fr][g],0,0,0);
                    } else {
                        x0v[fr] = __builtin_amdgcn_mfma_f32_16x16x32_f16(ah[fr], bhv, x0v[fr],0,0,0);
                        x1v[fr] = __builtin_amdgcn_mfma_f32_16x16x32_f16(ah[fr], blv, x1v[fr],0,0,0);
                        x1v[fr] = __builtin_amdgcn_mfma_f32_16x16x32_f16(al[fr], bhv, x1v[fr],0,0,0);
                    }
                }
            }
            __syncthreads();
        }
    }

    // ---- GRU epilogue ----
    const int rq = (lane>>4)<<2;
    const int j  = jb + wn*16 + (lane & 15);
    const float bhr = bh[j], bhz = bh[1024+j], bhn = bh[2048+j];
    float pvr, pvz, pvn;
    if constexpr(PREVEC){ pvr = prev[j]; pvz = prev[1024+j]; pvn = prev[2048+j]; }
#pragma unroll
    for (int fr=0; fr<4; ++fr){
        const int m0 = bm + wm*64 + fr*16 + rq;
#pragma unroll
        for (int q=0; q<4; ++q){
            const int m = m0 + q;
            float pre_r, pre_z, pre_n;
            if constexpr(PREVEC){ pre_r=pvr; pre_z=pvz; pre_n=pvn; }
            else {
                const float* pm = prev + (size_t)m*H3_ + j;
                pre_r = pm[0]; pre_z = pm[1024]; pre_n = pm[2048];
            }
            const float vr  = a0[fr][0][q] + a1[fr][0][q]*INV2K_ + pre_r + bhr;
            const float vz  = a0[fr][1][q] + a1[fr][1][q]*INV2K_ + pre_z + bhz;
            const float hn_ = a0[fr][2][q] + a1[fr][2][q]*INV2K_ + bhn;
            float in_;
            if constexpr(HASX) in_ = x0v[fr][q] + x1v[fr][q]*INV2K_ + pre_n;
            else               in_ = pre_n;
            const float r  = sigmoidf_(vr);
            const float zg = sigmoidf_(vz);
            const float nn = tanhf(in_ + r*hn_);
            const size_t off = ((size_t)(m>>4)*(KD>>3) + (j>>3))*128 + (size_t)((m&15)<<3) + (j&7);
            const float hv = (float)Ahp[off] + (float)Alp[off]*INV2K_;
            const float hnew = (1.f-zg)*nn + zg*hv;
            store_pl(Nh, Nl, off, hnew);
            if constexpr(WRITECTX) store_pl(Ch, Cl, off, hnew);   // beat: KD==1024
        }
    }
}

// ---------------------------------------------------------------------------
__global__ void init_xepl_k(const float* __restrict__ x0,
                            _Float16* __restrict__ xh, _Float16* __restrict__ xl){
    const int idx = blockIdx.x*256 + threadIdx.x;
    if (idx >= B_*E_) return;
    const int r = idx / E_, k = idx - r*E_;
    store_pl(xh, xl, fragoff(r, 1024+k, KXT_), x0[k]);
}

__global__ void init_givec_k(const float* __restrict__ b0, const float* __restrict__ bWi,
                             const float* __restrict__ bbi, float* __restrict__ giv){
    const int j = blockIdx.x*256 + threadIdx.x;       // 3072 exact
    giv[j] = b0[0]*bWi[j] + bbi[j];
}

// one wave per row: argmax over V (first-index tie-break), gather emb -> x_e planes
__global__ void argmax_emb_k(const float* __restrict__ logits,   // row stride 24*V_
                             const float* __restrict__ emb,
                             _Float16* __restrict__ xh, _Float16* __restrict__ xl,
                             float* __restrict__ samples){       // row stride 24
    const int row  = blockIdx.x*4 + (threadIdx.x >> 6);
    const int lane = threadIdx.x & 63;
    const float* lr = logits + (size_t)row * (24*V_);
    float best = -1e30f; int bi = 0;
#pragma unroll
    for (int v0=0; v0<V_; v0+=64){
        const int v = v0 + lane;
        const float val = lr[v];
        if (val > best){ best = val; bi = v; }
    }
#pragma unroll
    for (int off=32; off; off>>=1){
        const float ov = __shfl_xor(best, off);
        const int   oi = __shfl_xor(bi,  off);
        if (ov > best || (ov == best && oi < bi)){ best = ov; bi = oi; }
    }
    for (int k=lane; k<E_; k+=64)
        store_pl(xh, xl, fragoff(row, 1024+k, KXT_), emb[(size_t)bi*E_ + k]);
    if (lane == 0) samples[(size_t)row*24] = (float)bi;
}

// ---------------------------------------------------------------------------
extern "C" void kernel_launch(void* const* d_in, const int* in_sizes, int n_in,
                              void* d_out, int out_size, void* d_ws, size_t ws_size,
                              hipStream_t stream)
{
    const float* z    = (const float*)d_in[0];
    const float* emb  = (const float*)d_in[3];
    const float* z2W  = (const float*)d_in[4];
    const float* z2b  = (const float*)d_in[5];
    const float* b0   = (const float*)d_in[6];
    const float* bWi  = (const float*)d_in[7];
    const float* bWh  = (const float*)d_in[8];
    const float* bbi  = (const float*)d_in[9];
    const float* bbh  = (const float*)d_in[10];
    const float* hidW = (const float*)d_in[11];
    const float* hidb = (const float*)d_in[12];
    const float* inW  = (const float*)d_in[13];
    const float* inb  = (const float*)d_in[14];
    const float* x0   = (const float*)d_in[15];
    const float* tWi  = (const float*)d_in[16];
    const float* tWh  = (const float*)d_in[17];
    const float* tbi  = (const float*)d_in[18];
    const float* tbh  = (const float*)d_in[19];
    const float* outW = (const float*)d_in[20];
    const float* outb = (const float*)d_in[21];
    float* out = (float*)d_out;

    // ---- workspace carve ----
    char* p = (char*)d_ws;
    auto alloc_f = [&](size_t n){ float*    r = (float*)p;    p += n*4; return r; };
    auto alloc_h = [&](size_t n){ _Float16* r = (_Float16*)p; p += n*2; return r; };

    float* giv    = alloc_f(4096);
    float* ws_pre = alloc_f((size_t)B_*H3_);

    _Float16 *Th[2], *Tl[2];                    // tick planes, KD=1120 (h + x_e)
    for (int c=0;c<2;c++){ Th[c]=alloc_h((size_t)B_*KXT_); Tl[c]=alloc_h((size_t)B_*KXT_); }
    _Float16 *bPh[2], *bPl[2];                  // beat planes, KD=1024
    for (int c=0;c<2;c++){ bPh[c]=alloc_h((size_t)B_*H_); bPl[c]=alloc_h((size_t)B_*H_); }
    _Float16 *ctxh[BEATS_], *ctxl[BEATS_];
    for (int i=0;i<BEATS_;i++){ ctxh[i]=alloc_h((size_t)B_*H_); ctxl[i]=alloc_h((size_t)B_*H_); }
    _Float16 *beplh = alloc_h((size_t)B_*H_),  *bepll = alloc_h((size_t)B_*H_);
    _Float16 *zh    = alloc_h((size_t)B_*ZD_), *zl    = alloc_h((size_t)B_*ZD_);
    _Float16 *z2Wh  = alloc_h((size_t)H_*ZD_), *z2Wl  = alloc_h((size_t)H_*ZD_);
    _Float16 *bWhh  = alloc_h((size_t)H3_*H_), *bWhl  = alloc_h((size_t)H3_*H_);
    _Float16 *hidWh = alloc_h((size_t)H_*H_),  *hidWl = alloc_h((size_t)H_*H_);
    _Float16 *inWh  = alloc_h((size_t)H_*H_),  *inWl  = alloc_h((size_t)H_*H_);
    _Float16 *tWih  = alloc_h((size_t)H3_*KXT_), *tWil = alloc_h((size_t)H3_*KXT_);
    _Float16 *tWhh  = alloc_h((size_t)H3_*H_), *tWhl  = alloc_h((size_t)H3_*H_);
    _Float16 *outWh = alloc_h((size_t)V_*H_),  *outWl = alloc_h((size_t)V_*H_);

    const dim3 blk(256);
    auto G1 = [](long n){ return dim3((unsigned)((n+255)/256)); };

    // ---- one-time conversions ----
    cvt_pl<0><<<G1((long)B_*ZD_),  blk,0,stream>>>(z,    ZD_,   zh,    zl,    B_,  ZD_);
    cvt_pl<1><<<G1((long)H_*ZD_),  blk,0,stream>>>(z2W,  H_,    z2Wh,  z2Wl,  H_,  ZD_);
    cvt_pl<0><<<G1((long)H3_*H_),  blk,0,stream>>>(bWh,  H_,    bWhh,  bWhl,  H3_, H_);
    cvt_pl<1><<<G1((long)H_*H_),   blk,0,stream>>>(hidW, H_,    hidWh, hidWl, H_,  H_);
    cvt_pl<1><<<G1((long)H_*H_),   blk,0,stream>>>(inW,  H_,    inWh,  inWl,  H_,  H_);
    cvt_pl<0><<<G1((long)H3_*KXT_),blk,0,stream>>>(tWi,  KXT_,  tWih,  tWil,  H3_, KXT_);
    cvt_pl<0><<<G1((long)H3_*H_),  blk,0,stream>>>(tWh,  H_,    tWhh,  tWhl,  H3_, H_);
    cvt_pl<1><<<G1((long)H_*V_),   blk,0,stream>>>(outW, V_,    outWh, outWl, V_,  H_);

    init_xepl_k<<<G1((long)B_*E_), blk,0,stream>>>(x0, Th[0], Tl[0]);
    init_givec_k<<<H3_/256, blk,0,stream>>>(b0, bWi, bbi, giv);

    // ---- h_beat = selu(z @ z2W + z2b) -> beat planes P[0] ----
    mgemm<128,64,1,1,0,1><<<dim3(H_/64, B_/128), blk,0,stream>>>(
        zh, zl, ZD_, z2Wh, z2Wl, ZD_, 0, z2b, nullptr, 0, bPh[0], bPl[0], H_, ZD_);

    // ---- beat GRU: 4 fused steps ----
    for (int s=0; s<BEATS_; ++s){
        gru_gemm<1,0,1><<<dim3(H_/32, B_/128), blk,0,stream>>>(
            bPh[s&1], bPl[s&1], H_, bWhh, bWhl, nullptr, nullptr,
            giv, bbh, bPh[(s+1)&1], bPl[(s+1)&1], ctxh[s], ctxl[s]);
    }

    // ---- beats ----
    for (int i=0; i<BEATS_; ++i){
        // h_tick = selu(ctx @ hidW + hidb) -> tick planes T[0] (k<1024)
        mgemm<128,64,1,1,0,1><<<dim3(H_/64, B_/128), blk,0,stream>>>(
            ctxh[i], ctxl[i], H_, hidWh, hidWl, H_, 0, hidb, nullptr, 0, Th[0], Tl[0], KXT_, H_);
        // beat_emb = selu(ctx @ inW + inb)
        mgemm<128,64,1,1,0,1><<<dim3(H_/64, B_/128), blk,0,stream>>>(
            ctxh[i], ctxl[i], H_, inWh, inWl, H_, 0, inb, nullptr, 0, beplh, bepll, H_, H_);
        // pre = beat_emb @ tWi[:,96:].T + tbi  (fp32, gate-major)
        mgemm<128,64,0,1,1,0><<<dim3(H3_/64, B_/128), blk,0,stream>>>(
            beplh, bepll, H_, tWih, tWil, KXT_, E_, tbi, ws_pre, H3_, nullptr, nullptr, 0, H_);

        for (int t=0; t<TICKS_; ++t){
            const int col = i*TICKS_ + t;
            const int c = t & 1;
            // fused GRU: gh(K=1024) + gi_x(K=96) + pre + nonlinearity -> T[c^1]
            gru_gemm<0,1,0><<<dim3(H_/32, B_/128), blk,0,stream>>>(
                Th[c], Tl[c], KXT_, tWhh, tWhl, tWih, tWil,
                ws_pre, tbh, Th[c^1], Tl[c^1], nullptr, nullptr);
            // logits = relu(h @ outW + outb) -> d_out block
            mgemm<64,64,2,1,1,0><<<dim3(V_/64, B_/64), blk,0,stream>>>(
                Th[c^1], Tl[c^1], KXT_, outWh, outWl, H_, 0, outb,
                out + (size_t)col*V_, 24*V_, nullptr, nullptr, 0, H_);
            // argmax + emb gather -> x_e region of T[c^1]
            argmax_emb_k<<<B_/4, blk,0,stream>>>(out + (size_t)col*V_, emb,
                                                 Th[c^1], Tl[c^1], out + W0_ + col);
        }
    }
    (void)in_sizes; (void)n_in; (void)out_size; (void)ws_size;
}